// Round 2
// baseline (2294.645 us; speedup 1.0000x reference)
//
#include <hip/hip_runtime.h>
#include <hip/hip_bf16.h>

// Problem constants
#define Bz 16
#define Tz 32
#define Sz 128
#define Hz 256
#define NHz 8
#define DKz 32
#define TPz 4
#define Mz (Bz*Sz)          // 2048 rows
#define NSTEP (Tz-1)        // 31

typedef __bf16 bf16x8 __attribute__((ext_vector_type(8)));
typedef float  f32x4  __attribute__((ext_vector_type(4)));

// ---------------------------------------------------------------------------
// Weight prep: build K-major transposed bf16 weight blocks in workspace.
//  WT_enc1 [1792][256]: [Wq|Wk|Wv|Wg_h]^T for encoder (Wg rows 3:259)
//  WT_enc2 [1024][256]: enc Wg_ctx (rows 259:515)^T
//  WT_dec1 [1792][512]: k<256 = code -> (0 for qkv, Wg rows 0:256), k>=256 = dh -> (Wq|Wk|Wv|Wg rows 256:512)
//  WT_dec2 [1024][256]: dec Wg_ctx (rows 512:768)^T
//  WT_emb  [256][256]:  emb_W^T
// All source weights are float32.
// ---------------------------------------------------------------------------
__global__ __launch_bounds__(256) void prep_weights(
    const float* __restrict__ encWq, const float* __restrict__ encWk,
    const float* __restrict__ encWv, const float* __restrict__ encWg,
    const float* __restrict__ decWq, const float* __restrict__ decWk,
    const float* __restrict__ decWv, const float* __restrict__ decWg,
    const float* __restrict__ embW,
    __bf16* __restrict__ WT_enc1, __bf16* __restrict__ WT_enc2,
    __bf16* __restrict__ WT_dec1, __bf16* __restrict__ WT_dec2,
    __bf16* __restrict__ WT_emb)
{
    int id = blockIdx.x * 256 + threadIdx.x;
    if (id < 1792*256) {                       // WT_enc1
        int n = id >> 8, k = id & 255;
        float v;
        if (n < 256)      v = encWq[k*256 + n];
        else if (n < 512) v = encWk[k*256 + (n-256)];
        else if (n < 768) v = encWv[k*256 + (n-512)];
        else              v = encWg[(3+k)*1024 + (n-768)];
        WT_enc1[id] = (__bf16)v; return;
    }
    id -= 1792*256;
    if (id < 1024*256) {                       // WT_enc2
        int n = id >> 8, k = id & 255;
        WT_enc2[id] = (__bf16)encWg[(259+k)*1024 + n]; return;
    }
    id -= 1024*256;
    if (id < 1792*512) {                       // WT_dec1
        int n = id >> 9, k = id & 511;
        float v;
        if (k < 256) {
            v = (n < 768) ? 0.f : decWg[k*1024 + (n-768)];
        } else {
            int k2 = k - 256;
            if (n < 256)      v = decWq[k2*256 + n];
            else if (n < 512) v = decWk[k2*256 + (n-256)];
            else if (n < 768) v = decWv[k2*256 + (n-512)];
            else              v = decWg[(256+k2)*1024 + (n-768)];
        }
        WT_dec1[id] = (__bf16)v; return;
    }
    id -= 1792*512;
    if (id < 1024*256) {                       // WT_dec2
        int n = id >> 8, k = id & 255;
        WT_dec2[id] = (__bf16)decWg[(512+k)*1024 + n]; return;
    }
    id -= 1024*256;
    if (id < 256*256) {                        // WT_emb
        int n = id >> 8, k = id & 255;
        WT_emb[id] = (__bf16)embW[k*256 + n]; return;
    }
}

// ---------------------------------------------------------------------------
// GEMM: C[M,N] = A[M,K](bf16, K-major, stride lda) * BT[N,K](bf16, K-major)
// tile 128x128, BK=32, 256 threads = 4 waves (2x2), wave tile 64x64 (4x4 MFMA)
// EPI 0: store fp32 C (ldc).  EPI 1: sigmoid(v+bias[col]) -> bf16 C (ldc).
// ---------------------------------------------------------------------------
template<int EPI>
__global__ __launch_bounds__(256, 2) void gemm_bt(
    const __bf16* __restrict__ A, int lda,
    const __bf16* __restrict__ BT,
    float* __restrict__ Cf, __bf16* __restrict__ Cb, int ldc,
    const float* __restrict__ bias, int K)
{
    __shared__ __attribute__((aligned(16))) __bf16 As[128*32];
    __shared__ __attribute__((aligned(16))) __bf16 Bs[128*32];
    const int tid  = threadIdx.x;
    const int m0   = blockIdx.x << 7;
    const int n0   = blockIdx.y << 7;
    const int lane = tid & 63;
    const int w    = tid >> 6;
    const int quad = lane >> 4, lr = lane & 15;
    const int wm   = (w >> 1) << 6, wn = (w & 1) << 6;

    f32x4 acc[4][4] = {};

    const int r0 = tid >> 2;               // rows 0..63
    const int c0 = (tid & 3) << 3;         // k-chunk (8 bf16 = 16B)
    const __bf16* gA0 = A  + (size_t)(m0 + r0)      * lda + c0;
    const __bf16* gA1 = A  + (size_t)(m0 + r0 + 64) * lda + c0;
    const __bf16* gB0 = BT + (size_t)(n0 + r0)      * K   + c0;
    const __bf16* gB1 = BT + (size_t)(n0 + r0 + 64) * K   + c0;

    for (int k0 = 0; k0 < K; k0 += 32) {
        uint4 a0 = *(const uint4*)(gA0 + k0);
        uint4 a1 = *(const uint4*)(gA1 + k0);
        uint4 b0 = *(const uint4*)(gB0 + k0);
        uint4 b1 = *(const uint4*)(gB1 + k0);
        __syncthreads();
        ((uint4*)As)[tid]       = a0;
        ((uint4*)As)[tid + 256] = a1;
        ((uint4*)Bs)[tid]       = b0;
        ((uint4*)Bs)[tid + 256] = b1;
        __syncthreads();
        bf16x8 af[4], bfr[4];
        #pragma unroll
        for (int i = 0; i < 4; ++i)
            af[i]  = *(const bf16x8*)&As[(wm + i*16 + lr)*32 + quad*8];
        #pragma unroll
        for (int i = 0; i < 4; ++i)
            bfr[i] = *(const bf16x8*)&Bs[(wn + i*16 + lr)*32 + quad*8];
        #pragma unroll
        for (int mi = 0; mi < 4; ++mi)
            #pragma unroll
            for (int ni = 0; ni < 4; ++ni)
                acc[mi][ni] = __builtin_amdgcn_mfma_f32_16x16x32_bf16(
                    af[mi], bfr[ni], acc[mi][ni], 0, 0, 0);
    }

    #pragma unroll
    for (int mi = 0; mi < 4; ++mi) {
        #pragma unroll
        for (int ni = 0; ni < 4; ++ni) {
            const int col = n0 + wn + ni*16 + lr;
            #pragma unroll
            for (int r = 0; r < 4; ++r) {
                const int row = m0 + wm + mi*16 + quad*4 + r;
                float v = acc[mi][ni][r];
                if (EPI == 0) {
                    Cf[(size_t)row*ldc + col] = v;
                } else {
                    v += bias[col];
                    Cb[(size_t)row*ldc + col] = (__bf16)(1.f/(1.f + __expf(-v)));
                }
            }
        }
    }
}

// ---------------------------------------------------------------------------
// Attention over 4 spatial neighbors (offsets +2,+1,-1,-2; zero-padded => score 0)
// X layout [2048][1792]: q 0:256 | k 256:512 | v 512:768 | (gates 768:1792 untouched)
// one block per row m, thread = head*32 + d
// ---------------------------------------------------------------------------
__global__ __launch_bounds__(256, 4) void attn_k(
    const float* __restrict__ X, __bf16* __restrict__ ctxb)
{
    const int m = blockIdx.x;
    const int s = m & 127;
    const int tid = threadIdx.x;
    const float* row = X + (size_t)m * 1792;
    const float q = row[tid];
    const int offs[4] = {2, 1, -1, -2};
    float sc[4], vv[4];
    #pragma unroll
    for (int n = 0; n < 4; ++n) {
        const int s2 = s + offs[n];
        const bool ok = ((unsigned)s2 < 128u);
        const float* row2 = X + (size_t)(m + offs[n]) * 1792;
        float kk = ok ? row2[256 + tid] : 0.f;
        vv[n]    = ok ? row2[512 + tid] : 0.f;
        float p = q * kk;
        #pragma unroll
        for (int msk = 16; msk; msk >>= 1) p += __shfl_xor(p, msk);
        sc[n] = p * 0.17677669529663687f;   // 1/sqrt(32)
    }
    const float mx = fmaxf(fmaxf(sc[0], sc[1]), fmaxf(sc[2], sc[3]));
    float se = 0.f, ctx = 0.f;
    #pragma unroll
    for (int n = 0; n < 4; ++n) {
        float en = __expf(sc[n] - mx);
        se  += en;
        ctx += en * vv[n];
    }
    ctxb[(size_t)m*256 + tid] = (__bf16)(ctx / se);
}

// ---------------------------------------------------------------------------
// Encoder LSTM elementwise: z = XQ_gates + XG + x@Wg_x + bg ; update ec, ehb
// block per row m, thread = channel j.  input/Wg/bg are float32.
// ---------------------------------------------------------------------------
__global__ __launch_bounds__(256, 4) void enc_lstm_k(
    const float* __restrict__ XQ, const float* __restrict__ XG,
    const float* __restrict__ input, int t,
    const float* __restrict__ Wg, const float* __restrict__ bg,
    float* __restrict__ ec, __bf16* __restrict__ ehb)
{
    const int m = blockIdx.x, j = threadIdx.x;
    const int b = m >> 7, s = m & 127;
    const size_t xoff = ((size_t)(b*Tz + t)*Sz + s)*3;
    const float x0 = input[xoff], x1 = input[xoff+1], x2 = input[xoff+2];
    const float* qg = XQ + (size_t)m*1792 + 768;
    const float* g2 = XG + (size_t)m*1024;
    float z[4];
    #pragma unroll
    for (int g = 0; g < 4; ++g) {
        const int c = (g << 8) + j;
        z[g] = qg[c] + g2[c]
             + x0*Wg[c] + x1*Wg[1024+c] + x2*Wg[2048+c]
             + bg[c];
    }
    const float ig = 1.f/(1.f + __expf(-z[0]));
    const float fg = 1.f/(1.f + __expf(-z[1]));
    const float gg = tanhf(z[2]);
    const float og = 1.f/(1.f + __expf(-z[3]));
    const size_t idx = (size_t)m*256 + j;
    const float cn = fg*ec[idx] + ig*gg;
    ec[idx]  = cn;
    ehb[idx] = (__bf16)(og * tanhf(cn));
}

// ---------------------------------------------------------------------------
// Decoder LSTM elementwise (c := old dh) + fused out-projection dot
// writes dh (fp32), A4[:,256:512] (bf16), outbuf[m]
// ---------------------------------------------------------------------------
__global__ __launch_bounds__(256, 4) void dec_lstm_k(
    const float* __restrict__ XQ, const float* __restrict__ XG,
    const float* __restrict__ bg, const float* __restrict__ outW,
    float* __restrict__ dh, __bf16* __restrict__ A4,
    float* __restrict__ outbuf)
{
    const int m = blockIdx.x, j = threadIdx.x;
    const float* qg = XQ + (size_t)m*1792 + 768;
    const float* g2 = XG + (size_t)m*1024;
    float z[4];
    #pragma unroll
    for (int g = 0; g < 4; ++g) {
        const int c = (g << 8) + j;
        z[g] = qg[c] + g2[c] + bg[c];
    }
    const float ig = 1.f/(1.f + __expf(-z[0]));
    const float fg = 1.f/(1.f + __expf(-z[1]));
    const float gg = tanhf(z[2]);
    const float og = 1.f/(1.f + __expf(-z[3]));
    const size_t idx = (size_t)m*256 + j;
    const float c_old = dh[idx];
    const float cn = fg*c_old + ig*gg;
    const float hn = og * tanhf(cn);
    dh[idx] = hn;
    A4[(size_t)m*512 + 256 + j] = (__bf16)hn;

    float p = hn * outW[j];
    #pragma unroll
    for (int d = 32; d; d >>= 1) p += __shfl_down(p, d);
    __shared__ float red[4];
    if ((j & 63) == 0) red[j >> 6] = p;
    __syncthreads();
    if (j == 0) outbuf[m] = red[0] + red[1] + red[2] + red[3];
}

// ---------------------------------------------------------------------------
// Final assembly: out / In / num for scan steps t in [TP, T-2], fp32 output
// output shape [B, 27, S, 3]
// ---------------------------------------------------------------------------
__global__ __launch_bounds__(256) void assemble_k(
    const float* __restrict__ outbuf, const float* __restrict__ input,
    const float* __restrict__ outb, float* __restrict__ out)
{
    const int idx = blockIdx.x*256 + threadIdx.x;
    const int NT = NSTEP - TPz;                 // 27
    if (idx >= Bz*NT*Sz) return;
    const int s  = idx & 127;
    const int bi = idx >> 7;
    const int i  = bi % NT;
    const int b  = bi / NT;
    const int t  = i + TPz;
    const float ob = outb[0];
    const float o  = outbuf[t*Mz + (b<<7) + s] + ob;
    const float In = (s == 0)
        ? input[((size_t)(b*Tz + t + 1)*Sz + 0)*3 + 1]
        : outbuf[t*Mz + (b<<7) + s - 1] + ob;
    const float num = input[((size_t)(b*Tz + t)*Sz + s)*3 + 2] + In - o;
    const size_t base = ((size_t)(b*NT + i)*Sz + s)*3;
    out[base+0] = o;
    out[base+1] = In;
    out[base+2] = num;
}

// ---------------------------------------------------------------------------
extern "C" void kernel_launch(void* const* d_in, const int* in_sizes, int n_in,
                              void* d_out, int out_size, void* d_ws, size_t ws_size,
                              hipStream_t stream)
{
    const float* input = (const float*)d_in[0];
    const float* encWq = (const float*)d_in[1];
    const float* encWk = (const float*)d_in[2];
    const float* encWv = (const float*)d_in[3];
    const float* encWg = (const float*)d_in[4];
    const float* encbg = (const float*)d_in[5];
    const float* decWq = (const float*)d_in[6];
    const float* decWk = (const float*)d_in[7];
    const float* decWv = (const float*)d_in[8];
    const float* decWg = (const float*)d_in[9];
    const float* decbg = (const float*)d_in[10];
    const float* embW  = (const float*)d_in[11];
    const float* embb  = (const float*)d_in[12];
    const float* outW  = (const float*)d_in[13];
    const float* outb  = (const float*)d_in[14];

    char* ws = (char*)d_ws;
    size_t off = 0;
    auto alloc = [&](size_t bytes) -> void* {
        void* p = ws + off;
        off += (bytes + 255) & ~(size_t)255;
        return p;
    };
    __bf16* WT_enc1 = (__bf16*)alloc((size_t)1792*256*2);
    __bf16* WT_enc2 = (__bf16*)alloc((size_t)1024*256*2);
    __bf16* WT_dec1 = (__bf16*)alloc((size_t)1792*512*2);
    __bf16* WT_dec2 = (__bf16*)alloc((size_t)1024*256*2);
    __bf16* WT_emb  = (__bf16*)alloc((size_t)256*256*2);
    char*   zbase   = ws + off;
    __bf16* ehb = (__bf16*)alloc((size_t)Mz*256*2);   // encoder h (bf16 state)
    __bf16* A4  = (__bf16*)alloc((size_t)Mz*512*2);   // [code | dh] bf16
    float*  ec  = (float*) alloc((size_t)Mz*256*4);   // encoder c (fp32 state)
    float*  dh  = (float*) alloc((size_t)Mz*256*4);   // decoder h (fp32 state)
    size_t  zbytes = (size_t)((ws + off) - zbase);
    __bf16* ctxb   = (__bf16*)alloc((size_t)Mz*256*2);
    float*  XQ     = (float*) alloc((size_t)Mz*1792*4);
    float*  XG     = (float*) alloc((size_t)Mz*1024*4);
    float*  outbuf = (float*) alloc((size_t)NSTEP*Mz*4);

    hipMemsetAsync(zbase, 0, zbytes, stream);
    prep_weights<<<7680, 256, 0, stream>>>(encWq, encWk, encWv, encWg,
                                           decWq, decWk, decWv, decWg, embW,
                                           WT_enc1, WT_enc2, WT_dec1, WT_dec2, WT_emb);

    for (int t = 0; t < NSTEP; ++t) {
        // encoder: [q|k|v|gates_h] = ehb @ WT_enc1^T
        gemm_bt<0><<<dim3(16,14), 256, 0, stream>>>(ehb, 256, WT_enc1, XQ, nullptr, 1792, nullptr, 256);
        attn_k<<<Mz, 256, 0, stream>>>(XQ, ctxb);
        gemm_bt<0><<<dim3(16,8), 256, 0, stream>>>(ctxb, 256, WT_enc2, XG, nullptr, 1024, nullptr, 256);
        enc_lstm_k<<<Mz, 256, 0, stream>>>(XQ, XG, input, t, encWg, encbg, ec, ehb);
        // code = sigmoid(eh @ embW + embb) -> A4[:, 0:256]
        gemm_bt<1><<<dim3(16,2), 256, 0, stream>>>(ehb, 256, WT_emb, nullptr, A4, 512, embb, 256);
        // decoder: [q|k|v|gates_{code,h}] = [code|dh] @ WT_dec1^T
        gemm_bt<0><<<dim3(16,14), 256, 0, stream>>>(A4, 512, WT_dec1, XQ, nullptr, 1792, nullptr, 512);
        attn_k<<<Mz, 256, 0, stream>>>(XQ, ctxb);
        gemm_bt<0><<<dim3(16,8), 256, 0, stream>>>(ctxb, 256, WT_dec2, XG, nullptr, 1024, nullptr, 256);
        dec_lstm_k<<<Mz, 256, 0, stream>>>(XQ, XG, decbg, outW, dh, A4, outbuf + t*Mz);
    }
    assemble_k<<<(Bz*(NSTEP-TPz)*Sz + 255)/256, 256, 0, stream>>>(outbuf, input, outb, (float*)d_out);
}